// Round 5
// baseline (69.990 us; speedup 1.0000x reference)
//
#include <hip/hip_runtime.h>
#include <math.h>

#define KC 3
#define S 12
#define SS 1728
#define AB 32
#define TLEN 64
#define NTHREADS 448
#define NWAVES 7
#define NSLICE 432
#define LN2F 0.69314718055994530942f

__global__ __launch_bounds__(NTHREADS, 2)
void hmm_fwd_kernel(const int* __restrict__ ys,
                    const float* __restrict__ transition,  // [3][12][12]
                    const float* __restrict__ emission,    // [3][12][32]
                    const float* __restrict__ choice,      // [3]
                    const float* __restrict__ prior,       // [3][12]
                    float* __restrict__ out)
{
    // Natural layouts. A0 [0,1728), A1 [1728,3456), A2 [3456,5184).
    __shared__ __align__(16) float ABUF[3*SS];
    __shared__ __align__(16) float BETA[SS];
    __shared__ __align__(16) float ECt[KC*AB*S];   // [k][y][j], rows of 12
    __shared__ float T_s[KC][S][S];
    __shared__ float p_lin[KC][S];
    __shared__ float c_lin[KC];
    __shared__ int   ys_s[TLEN];
    __shared__ float wsum[NWAVES];

    const int tid = threadIdx.x;

    // ---------------- setup: linear-space tables ----------------
    if (tid < TLEN) ys_s[tid] = ys[tid];

    if (tid == 0) {
        float m = fmaxf(fmaxf(choice[0], choice[1]), choice[2]);
        float e0 = __expf(choice[0]-m), e1 = __expf(choice[1]-m), e2 = __expf(choice[2]-m);
        float inv = 1.f / (e0+e1+e2);
        c_lin[0] = e0*inv; c_lin[1] = e1*inv; c_lin[2] = e2*inv;
    }
    if (tid >= 1 && tid < 1 + KC) {
        int k = tid - 1;
        float m = -INFINITY;
        #pragma unroll
        for (int i = 0; i < S; ++i) m = fmaxf(m, prior[k*S + i]);
        float ev[S]; float s = 0.f;
        #pragma unroll
        for (int i = 0; i < S; ++i) { ev[i] = __expf(prior[k*S + i] - m); s += ev[i]; }
        float inv = 1.f / s;
        #pragma unroll
        for (int i = 0; i < S; ++i) p_lin[k][i] = ev[i] * inv;
    }
    if (tid >= 64 && tid < 64 + KC*S) {
        int r = tid - 64;
        int k = r / S, i = r % S;
        const float* row = transition + (k*S + i)*S;
        float m = -INFINITY;
        #pragma unroll
        for (int j = 0; j < S; ++j) m = fmaxf(m, row[j]);
        float ev[S]; float s = 0.f;
        #pragma unroll
        for (int j = 0; j < S; ++j) { ev[j] = __expf(row[j] - m); s += ev[j]; }
        float inv = 1.f / s;
        #pragma unroll
        for (int j = 0; j < S; ++j) T_s[k][i][j] = ev[j] * inv;
    }
    if (tid >= 128 && tid < 128 + KC*S) {    // emission -> ECt[k][y][j] = C[k]*softmax
        int r = tid - 128;
        int k = r / S, sj = r % S;
        float cm = fmaxf(fmaxf(choice[0], choice[1]), choice[2]);
        float ce = __expf(choice[k]-cm) /
                   (__expf(choice[0]-cm) + __expf(choice[1]-cm) + __expf(choice[2]-cm));
        const float* row = emission + (k*S + sj)*AB;
        float m = -INFINITY;
        #pragma unroll
        for (int a = 0; a < AB; ++a) m = fmaxf(m, row[a]);
        float ev[AB]; float s = 0.f;
        #pragma unroll
        for (int a = 0; a < AB; ++a) { ev[a] = __expf(row[a] - m); s += ev[a]; }
        float inv = ce / s;
        #pragma unroll
        for (int a = 0; a < AB; ++a) ECt[(k*AB + a)*S + sj] = ev[a] * inv;
    }
    __syncthreads();

    // ---------------- per-thread statics ----------------
    const bool active = tid < NSLICE;
    const int sk = tid / 144;          // chain
    const int q  = tid % 144;

    // per-thread base pointers (precomputed; offsets in the loop are literals)
    const float* rdp = nullptr;        // beta gather base
    float*       wrp = nullptr;        // plane write base
    float4 T4[S][3];

    if (active) {
        if (sk == 0)      { rdp = &BETA[q];                     wrp = &ABUF[q]; }
        else if (sk == 1) { int b = (q/12)*144 + (q%12);
                            rdp = &BETA[b];                     wrp = &ABUF[SS + b]; }
        else              { rdp = &BETA[12*q];                  wrp = &ABUF[2*SS + 12*q]; }

        #pragma unroll
        for (int i = 0; i < S; ++i) {
            #pragma unroll
            for (int c = 0; c < 3; ++c) {
                T4[i][c] = *reinterpret_cast<const float4*>(&T_s[sk][i][4*c]);
                asm volatile("" : "+v"(T4[i][c].x), "+v"(T4[i][c].y),
                                  "+v"(T4[i][c].z), "+v"(T4[i][c].w));
            }
        }

        // init A0[s,k] = prod of prior probs * C[k]
        float pq = (sk == 0) ? p_lin[1][q/12] * p_lin[2][q%12]
                 : (sk == 1) ? p_lin[0][q/12] * p_lin[2][q%12]
                 :             p_lin[0][q/12] * p_lin[1][q%12];
        float ck = c_lin[sk];
        if (sk == 0) {
            #pragma unroll
            for (int j = 0; j < S; ++j) wrp[j*144] = p_lin[0][j] * pq * ck;
        } else if (sk == 1) {
            #pragma unroll
            for (int j = 0; j < S; ++j) wrp[j*12] = p_lin[1][j] * pq * ck;
        } else {
            #pragma unroll
            for (int j = 0; j < S; ++j) wrp[j] = p_lin[2][j] * pq * ck;
        }
    }
    __syncthreads();

    // ---------------- 64 steps, 2 barriers each ----------------
    float logR = 0.f, invR = 1.f;

    for (int t = 0; t < TLEN; ++t) {
        const int y = ys_s[t];
        float4 e0, e1, e2;

        if (active) {
            // phase 1: beta for 4 contiguous states (all wide, conflict-free)
            float4 a0 = *reinterpret_cast<const float4*>(&ABUF[4*tid]);
            float4 a1 = *reinterpret_cast<const float4*>(&ABUF[SS + 4*tid]);
            float4 a2 = *reinterpret_cast<const float4*>(&ABUF[2*SS + 4*tid]);
            float4 b4;
            b4.x = a0.x + a1.x + a2.x;
            b4.y = a0.y + a1.y + a2.y;
            b4.z = a0.z + a1.z + a2.z;
            b4.w = a0.w + a1.w + a2.w;
            *reinterpret_cast<float4*>(&BETA[4*tid]) = b4;
            // ecol prefetch for this step (read-only table)
            const float* eb = &ECt[(sk*AB + y)*S];
            e0 = *reinterpret_cast<const float4*>(&eb[0]);
            e1 = *reinterpret_cast<const float4*>(&eb[4]);
            e2 = *reinterpret_cast<const float4*>(&eb[8]);
        }
        __syncthreads();   // barrier A: BETA ready

        float o[S];
        if (active) {
            // gather 12 betas along own chain (literal offsets -> ds_read2/b128)
            float bv[S];
            if (sk == 0) {
                #pragma unroll
                for (int i = 0; i < S; ++i) bv[i] = rdp[i*144];
            } else if (sk == 1) {
                #pragma unroll
                for (int i = 0; i < S; ++i) bv[i] = rdp[i*12];
            } else {
                float4 r0 = *reinterpret_cast<const float4*>(&rdp[0]);
                float4 r1 = *reinterpret_cast<const float4*>(&rdp[4]);
                float4 r2 = *reinterpret_cast<const float4*>(&rdp[8]);
                bv[0]=r0.x; bv[1]=r0.y; bv[2] =r0.z; bv[3] =r0.w;
                bv[4]=r1.x; bv[5]=r1.y; bv[6] =r1.z; bv[7] =r1.w;
                bv[8]=r2.x; bv[9]=r2.y; bv[10]=r2.z; bv[11]=r2.w;
            }

            float4 acc0 = {0,0,0,0}, acc1 = {0,0,0,0}, acc2 = {0,0,0,0};
            #pragma unroll
            for (int i = 0; i < S; ++i) {
                const float b = bv[i];
                acc0.x += b*T4[i][0].x; acc0.y += b*T4[i][0].y;
                acc0.z += b*T4[i][0].z; acc0.w += b*T4[i][0].w;
                acc1.x += b*T4[i][1].x; acc1.y += b*T4[i][1].y;
                acc1.z += b*T4[i][1].z; acc1.w += b*T4[i][1].w;
                acc2.x += b*T4[i][2].x; acc2.y += b*T4[i][2].y;
                acc2.z += b*T4[i][2].z; acc2.w += b*T4[i][2].w;
            }
            o[0] = acc0.x*e0.x*invR; o[1] = acc0.y*e0.y*invR;
            o[2] = acc0.z*e0.z*invR; o[3] = acc0.w*e0.w*invR;
            o[4] = acc1.x*e1.x*invR; o[5] = acc1.y*e1.y*invR;
            o[6] = acc1.z*e1.z*invR; o[7] = acc1.w*e1.w*invR;
            o[8] = acc2.x*e2.x*invR; o[9] = acc2.y*e2.y*invR;
            o[10]= acc2.z*e2.z*invR; o[11]= acc2.w*e2.w*invR;

            // scatter to own plane (literal offsets -> ds_write2/b128)
            if (sk == 0) {
                #pragma unroll
                for (int j = 0; j < S; ++j) wrp[j*144] = o[j];
            } else if (sk == 1) {
                #pragma unroll
                for (int j = 0; j < S; ++j) wrp[j*12] = o[j];
            } else {
                float4* pw = reinterpret_cast<float4*>(wrp);
                pw[0] = make_float4(o[0], o[1], o[2],  o[3]);
                pw[1] = make_float4(o[4], o[5], o[6],  o[7]);
                pw[2] = make_float4(o[8], o[9], o[10], o[11]);
            }
        }

        if ((t & 7) == 7) {
            float part = 0.f;
            if (active) {
                #pragma unroll
                for (int j = 0; j < S; ++j) part += o[j];
            }
            #pragma unroll
            for (int w = 32; w > 0; w >>= 1) part += __shfl_xor(part, w);
            if ((tid & 63) == 0) wsum[tid >> 6] = part;
        }
        __syncthreads();   // barrier B: planes (and wsum on reduce steps) ready

        if ((t & 7) == 7 && t < TLEN-1) {
            float R = wsum[0];
            #pragma unroll
            for (int w = 1; w < NWAVES; ++w) R += wsum[w];
            invR = __builtin_amdgcn_rcpf(R);
            logR += __log2f(R);
        } else {
            invR = 1.f;
        }
    }

    // final: total mass at t=63 is in wsum (normalizer unapplied)
    if (tid == 0) {
        float R = wsum[0];
        #pragma unroll
        for (int w = 1; w < NWAVES; ++w) R += wsum[w];
        out[0] = LN2F * (__log2f(R) + logR);
    }
}

extern "C" void kernel_launch(void* const* d_in, const int* in_sizes, int n_in,
                              void* d_out, int out_size, void* d_ws, size_t ws_size,
                              hipStream_t stream) {
    const int*   ys         = (const int*)  d_in[0];
    const float* transition = (const float*)d_in[1];
    const float* emission   = (const float*)d_in[2];
    const float* choice     = (const float*)d_in[3];
    const float* prior      = (const float*)d_in[4];
    float* out = (float*)d_out;

    hipLaunchKernelGGL(hmm_fwd_kernel, dim3(1), dim3(NTHREADS), 0, stream,
                       ys, transition, emission, choice, prior, out);
}